// Round 1
// 142.460 us; speedup vs baseline: 1.1233x; 1.1233x over previous
//
#include <hip/hip_runtime.h>

typedef _Float16 half8 __attribute__((ext_vector_type(8)));
typedef float floatx4 __attribute__((ext_vector_type(4)));

constexpr int C = 32, H = 512, W = 512, HW = H * W;
constexpr int TBH = 8, TBW = 64;   // output tile per block (rows x px), all 32 C_out
constexpr int RR  = TBH + 2;       // staged input rows  (h0-1 .. h0+8)
constexpr int PX  = 72;            // staged px per row  (w0-4 .. w0+67, f4-aligned)

__device__ __forceinline__ unsigned pack2h(float lo, float hi) {
    unsigned a = (unsigned)__builtin_bit_cast(unsigned short, (_Float16)lo);
    unsigned b = (unsigned)__builtin_bit_cast(unsigned short, (_Float16)hi);
    return a | (b << 16);
}

// ---- tiny kernel: weights -> per-lane fp16 A-fragment uint4s (18.4 KB, L2-hot)
__global__ __launch_bounds__(256) void pack_w(const float* __restrict__ weight,
                                              uint4* __restrict__ wp) {
    int j = blockIdx.x * 256 + threadIdx.x;
    if (j >= 1152) return;                       // 9 taps * 2 halves * 64 lanes
    int lane = j & 63, half = (j >> 6) & 1, tap = j >> 7;
    int o = half * 16 + (lane & 15), q = lane >> 4;
    uint4 v;
    v.x = pack2h(weight[(o * 32 + q * 8 + 0) * 9 + tap], weight[(o * 32 + q * 8 + 1) * 9 + tap]);
    v.y = pack2h(weight[(o * 32 + q * 8 + 2) * 9 + tap], weight[(o * 32 + q * 8 + 3) * 9 + tap]);
    v.z = pack2h(weight[(o * 32 + q * 8 + 4) * 9 + tap], weight[(o * 32 + q * 8 + 5) * 9 + tap]);
    v.w = pack2h(weight[(o * 32 + q * 8 + 6) * 9 + tap], weight[(o * 32 + q * 8 + 7) * 9 + tap]);
    wp[j] = v;
}

// ---- fused: stage x-tile (NCHW fp32 -> LDS NHWC fp16, XOR-swizzled) + depth
//      exp-pack in LDS, then MFMA conv. No global intermediate.
__global__ __launch_bounds__(256, 2) void depthconv_fused(
    const float* __restrict__ x, const float* __restrict__ depth,
    const uint4* __restrict__ wp, const float* __restrict__ bias,
    float* __restrict__ out)
{
    // x tile: [RR][PX] pixels * 64 B (32ch fp16). 16B-chunk q swizzled by
    // q ^= (px>>2)&3  -> ds_read_b128 2-way (free), ds_write_b32 ~4-way (tiny).
    __shared__ __attribute__((aligned(16))) unsigned xsl[RR * PX * 16];
    __shared__ float2 dsim[RR][PX];              // (exp(-8.3d), exp(+8.3d))

    const int bid  = blockIdx.x;                 // b(2) x hseg(64) x wseg(8)
    const int wseg = bid & 7, hseg = (bid >> 3) & 63, b = bid >> 9;
    const int h0 = hseg * TBH, w0 = wseg * TBW;
    const int tid = threadIdx.x;

    // ---- stage 1a: x -> LDS. unit = (cpair, row, f4): 2 float4 loads,
    // 4 packed dword LDS writes. 2880 units / 256 thr = 11.25 each.
    for (int u = tid; u < 16 * RR * 18; u += 256) {
        int f4 = u % 18, t = u / 18;
        int r = t % RR, cp = t / RR;
        int h = h0 - 1 + r, wst = w0 - 4 + f4 * 4;
        bool valid = (h >= 0) && (h < H) && (wst >= 0) && (wst < W);  // whole-f4 granular
        float4 va = {0.f, 0.f, 0.f, 0.f}, vb = {0.f, 0.f, 0.f, 0.f};
        if (valid) {
            const float* xb = x + ((size_t)(b * C + 2 * cp)) * HW + h * W + wst;
            va = *(const float4*)xb;
            vb = *(const float4*)(xb + HW);
        }
        int swz = (((cp >> 2) ^ (f4 & 3)) << 2) | (cp & 3);   // (px>>2)&3 == f4&3
        unsigned* dst = &xsl[(r * PX + f4 * 4) * 16 + swz];
        dst[0]  = pack2h(va.x, vb.x);
        dst[16] = pack2h(va.y, vb.y);
        dst[32] = pack2h(va.z, vb.z);
        dst[48] = pack2h(va.w, vb.w);
    }

    // ---- stage 1b: depth -> (em, ep) in LDS (border -> (0,0): sim*x == 0 there)
    if (tid < RR * 18) {
        int f4 = tid % 18, r = tid / 18;
        int h = h0 - 1 + r, wst = w0 - 4 + f4 * 4;
        bool valid = (h >= 0) && (h < H) && (wst >= 0) && (wst < W);
        float4 dv = {0.f, 0.f, 0.f, 0.f};
        if (valid) dv = *(const float4*)(depth + (size_t)b * HW + h * W + wst);
        float dd[4] = {dv.x, dv.y, dv.z, dv.w};
        #pragma unroll
        for (int j = 0; j < 4; ++j) {
            dsim[r][f4 * 4 + j] = valid
                ? make_float2(__expf(-8.3f * dd[j]), __expf(8.3f * dd[j]))
                : make_float2(0.f, 0.f);
        }
    }

    const int lane = tid & 63, wid = tid >> 6;
    const int nn = lane & 15, q = lane >> 4;

    // A fragments (L2-hot, amortized over 144 MFMAs/wave) — before the barrier
    half8 af[2][9];
    #pragma unroll
    for (int tap = 0; tap < 9; ++tap) {
        af[0][tap] = __builtin_bit_cast(half8, wp[(tap * 2 + 0) * 64 + lane]);
        af[1][tap] = __builtin_bit_cast(half8, wp[(tap * 2 + 1) * 64 + lane]);
    }

    floatx4 acc[TBH][2];                         // C/D: col=nn, row(o)=4q+i
    #pragma unroll
    for (int o = 0; o < TBH; ++o)
        #pragma unroll
        for (int i = 0; i < 4; ++i) {
            acc[o][0][i] = bias[q * 4 + i];
            acc[o][1][i] = bias[16 + q * 4 + i];
        }

    __syncthreads();

    const int pc = wid * 16 + nn;                // tile-local output px 0..63
    float2 dc[TBH];                              // center (em,ep) per output row
    #pragma unroll
    for (int o = 0; o < TBH; ++o) dc[o] = dsim[o + 1][pc + 4];

    // ---- stage 2: per input row r, load 3 B-raws once, feed the <=3 output
    // rows that tap it (ki = r - o). 30 ds_read_b128 -> 144 MFMAs per wave.
    #pragma unroll
    for (int r = 0; r < RR; ++r) {
        uint4 xraw[3]; float2 dn[3];
        #pragma unroll
        for (int kj = 0; kj < 3; ++kj) {
            int p = pc + 3 + kj;                 // global w = (w0+pc) + kj - 1
            xraw[kj] = *(const uint4*)&xsl[(r * PX + p) * 16 + ((q ^ ((p >> 2) & 3)) << 2)];
            dn[kj] = dsim[r][p];
        }
        #pragma unroll
        for (int kj = 0; kj < 3; ++kj) {
            #pragma unroll
            for (int ki = 0; ki < 3; ++ki) {
                int o = r - ki;
                if (o < 0 || o >= TBH) continue; // resolved at compile time
                int tap = ki * 3 + kj;
                float s = fminf(dn[kj].y * dc[o].x, dn[kj].x * dc[o].y); // exp(-8.3|dc-dn|)
                _Float16 hs = (_Float16)s;
                half8 sv = { hs, hs, hs, hs, hs, hs, hs, hs };
                half8 bf = __builtin_bit_cast(half8, xraw[kj]) * sv;    // 4x v_pk_mul_f16
                acc[o][0] = __builtin_amdgcn_mfma_f32_16x16x32_f16(af[0][tap], bf, acc[o][0], 0, 0, 0);
                acc[o][1] = __builtin_amdgcn_mfma_f32_16x16x32_f16(af[1][tap], bf, acc[o][1], 0, 0, 0);
            }
        }
    }

    // ---- epilogue
    const int pw = w0 + pc;
    #pragma unroll
    for (int o = 0; o < TBH; ++o) {
        float* op = out + (size_t)b * C * HW + (size_t)(h0 + o) * W + pw;
        #pragma unroll
        for (int i = 0; i < 4; ++i) {
            op[(size_t)(q * 4 + i) * HW]      = acc[o][0][i];
            op[(size_t)(16 + q * 4 + i) * HW] = acc[o][1][i];
        }
    }
}

extern "C" void kernel_launch(void* const* d_in, const int* in_sizes, int n_in,
                              void* d_out, int out_size, void* d_ws, size_t ws_size,
                              hipStream_t stream) {
    const float* x      = (const float*)d_in[0];
    const float* depth  = (const float*)d_in[1];
    const float* weight = (const float*)d_in[2];
    const float* bias   = (const float*)d_in[3];
    float* out          = (float*)d_out;

    uint4* wpk = (uint4*)d_ws;                   // 18.4 KB, only ws user now

    hipLaunchKernelGGL(pack_w, dim3(5), dim3(256), 0, stream, weight, wpk);
    hipLaunchKernelGGL(depthconv_fused, dim3(2 * 64 * 8), dim3(256), 0, stream,
                       x, depth, wpk, bias, out);
}